// Round 6
// baseline (415.067 us; speedup 1.0000x reference)
//
#include <hip/hip_runtime.h>
#include <math.h>

#define N_NODES 100000
#define F_IN    512
#define E_EDGES 3200000

#define NR     16               // node ranges
#define RN     6250             // nodes per range (NR*RN == N_NODES)
#define SB     512              // bucket scan blocks
#define SCHUNK (E_EDGES / SB)   // 6250 edges per scan block
#define CAP    204800           // record capacity per range (mean 200000, +11 sigma)
#define SLICES 32               // slice blocks per range for LDS scatter
#define JMASK  0x1FFF           // 13 bits for j in [0,RN)

// ============ init: range cursors + logit ============
__global__ void k_init(int* __restrict__ cursor, float* __restrict__ logit) {
    int t = threadIdx.x;
    if (t < NR) cursor[t] = t * CAP;
    if (t == 0) logit[0] = 0.0f;
}

// ============ bucket edges by col-range into packed records (one pass) ============
__global__ __launch_bounds__(256) void k_bucket(const int* __restrict__ row,
                                                const int* __restrict__ col,
                                                const float* __restrict__ w,
                                                int* __restrict__ cursor,
                                                unsigned* __restrict__ sidx,
                                                float* __restrict__ sw) {
    __shared__ int hcnt[NR];
    __shared__ int hbase[NR];
    int t = threadIdx.x;
    if (t < NR) hcnt[t] = 0;
    __syncthreads();
    int base = blockIdx.x * SCHUNK;
    // phase 1: count per range
    for (int i = t; i < SCHUNK; i += 256) {
        int r = col[base + i] / RN;
        atomicAdd(&hcnt[r], 1);
    }
    __syncthreads();
    if (t < NR) {
        hbase[t] = atomicAdd(&cursor[t], hcnt[t]);   // reserve contiguous run
        hcnt[t] = 0;                                  // reuse as intra-block rank
    }
    __syncthreads();
    // phase 2: scatter records (col re-read hits L1/L2)
    for (int i = t; i < SCHUNK; i += 256) {
        int c = col[base + i];
        int r = c / RN;
        int j = c - r * RN;
        int rank = atomicAdd(&hcnt[r], 1);
        int slot = hbase[r] + rank;
        sidx[slot] = (unsigned)j | ((unsigned)row[base + i] << 13);
        sw[slot]   = w[base + i];
    }
}

// ============ deg scatter over bucketed records (LDS tile, slices) ============
__global__ __launch_bounds__(1024) void k_deg_s(const unsigned* __restrict__ sidx,
                                                const float* __restrict__ sw,
                                                const int* __restrict__ cursor,
                                                float* __restrict__ rep_deg) {
    __shared__ float sdeg[RN];
    int r = blockIdx.x / SLICES, s = blockIdx.x % SLICES;
    int lo_r = r * CAP, hi_r = cursor[r];
    int len = hi_r - lo_r;
    int lo = lo_r + len * s / SLICES;
    int hi = lo_r + len * (s + 1) / SLICES;
    for (int j = threadIdx.x; j < RN; j += 1024) sdeg[j] = 0.0f;
    __syncthreads();
    for (int i = lo + threadIdx.x; i < hi; i += 1024) {
        unsigned u = sidx[i];
        atomicAdd(&sdeg[u & JMASK], sw[i]);
    }
    __syncthreads();
    float* out = rep_deg + (size_t)blockIdx.x * RN;
    for (int j = threadIdx.x; j < RN; j += 1024) out[j] = sdeg[j];
}

// ============ reduce replicas -> dis = rsqrt(1+deg) ============
__global__ void k_dis(const float* __restrict__ rep_deg,
                      float* __restrict__ dis) {
    int i = blockIdx.x * blockDim.x + threadIdx.x;
    if (i < N_NODES) {
        int r = i / RN, j = i - r * RN;
        const float* base = rep_deg + (size_t)(r * SLICES) * RN + j;
        float d = 1.0f;
#pragma unroll
        for (int p = 0; p < SLICES; ++p) d += base[p * RN];
        dis[i] = rsqrtf(d);
    }
}

// ============ g = (x @ W) * dis  (wave-per-row, memory-bound) ============
__global__ __launch_bounds__(256) void k_gemv(const float* __restrict__ x,
                                              const float* __restrict__ W,
                                              const float* __restrict__ dis,
                                              float* __restrict__ g) {
    int row  = (blockIdx.x * blockDim.x + threadIdx.x) >> 6;
    int lane = threadIdx.x & 63;
    if (row >= N_NODES) return;
    const float* xr = x + (size_t)row * F_IN;
    float a0 = 0.0f, a1 = 0.0f;
#pragma unroll
    for (int c = 0; c < 2; ++c) {
        int k = c * 256 + lane * 4;
        float4 xv  = *(const float4*)(xr + k);
        float4 w01 = *(const float4*)(W + 2 * k);
        float4 w23 = *(const float4*)(W + 2 * k + 4);
        a0 += xv.x * w01.x + xv.y * w01.z + xv.z * w23.x + xv.w * w23.z;
        a1 += xv.x * w01.y + xv.y * w01.w + xv.z * w23.y + xv.w * w23.w;
    }
#pragma unroll
    for (int off = 32; off > 0; off >>= 1) {
        a0 += __shfl_down(a0, off, 64);
        a1 += __shfl_down(a1, off, 64);
    }
    if (lane == 0) {
        float d = dis[row];
        g[2 * row]     = a0 * d;
        g[2 * row + 1] = a1 * d;
    }
}

// ============ message scatter over bucketed records ============
__global__ __launch_bounds__(1024) void k_prop_s(const unsigned* __restrict__ sidx,
                                                 const float* __restrict__ sw,
                                                 const int* __restrict__ cursor,
                                                 const float* __restrict__ g,
                                                 float* __restrict__ rep_acc) {
    __shared__ float sacc[RN * 2];
    int r = blockIdx.x / SLICES, s = blockIdx.x % SLICES;
    int lo_r = r * CAP, hi_r = cursor[r];
    int len = hi_r - lo_r;
    int lo = lo_r + len * s / SLICES;
    int hi = lo_r + len * (s + 1) / SLICES;
    for (int j = threadIdx.x; j < RN * 2; j += 1024) sacc[j] = 0.0f;
    __syncthreads();
    for (int i = lo + threadIdx.x; i < hi; i += 1024) {
        unsigned u = sidx[i];
        int j  = u & JMASK;
        int rr = u >> 13;
        float we = sw[i];
        float2 gv = *(const float2*)(g + 2 * rr);
        atomicAdd(&sacc[2 * j],     gv.x * we);
        atomicAdd(&sacc[2 * j + 1], gv.y * we);
    }
    __syncthreads();
    float* out = rep_acc + (size_t)blockIdx.x * (RN * 2);
    for (int j = threadIdx.x; j < RN * 2; j += 1024) out[j] = sacc[j];
}

// ============ epilogue: replica-reduce + self-loop + relu + fc dot ============
__global__ __launch_bounds__(256) void k_epilogue(const float* __restrict__ rep_acc,
                                                  const float* __restrict__ g,
                                                  const float* __restrict__ dis,
                                                  const float* __restrict__ b,
                                                  const float* __restrict__ fc_w,
                                                  float* __restrict__ logit) {
    int i = blockIdx.x * blockDim.x + threadIdx.x;
    float partial = 0.0f;
    if (i < N_NODES) {
        int r = i / RN, j = i - r * RN;
        const float2* base = (const float2*)rep_acc + (size_t)(r * SLICES) * RN + j;
        float o0 = 0.0f, o1 = 0.0f;
#pragma unroll
        for (int p = 0; p < SLICES; ++p) { float2 v = base[p * RN]; o0 += v.x; o1 += v.y; }
        float d = dis[i];
        o0 = (o0 + g[2 * i])     * d + b[0];   // self-loop term: g[i]*dis[i]
        o1 = (o1 + g[2 * i + 1]) * d + b[1];
        o0 = fmaxf(o0, 0.0f); o1 = fmaxf(o1, 0.0f);
        partial = o0 * fc_w[2 * i] + o1 * fc_w[2 * i + 1];
    }
#pragma unroll
    for (int off = 32; off > 0; off >>= 1)
        partial += __shfl_down(partial, off, 64);
    __shared__ float sdata[4];
    int lane = threadIdx.x & 63, wid = threadIdx.x >> 6;
    if (lane == 0) sdata[wid] = partial;
    __syncthreads();
    if (threadIdx.x == 0)
        atomicAdd(logit, sdata[0] + sdata[1] + sdata[2] + sdata[3]);
}

__global__ void k_sigmoid(const float* __restrict__ logit,
                          const float* __restrict__ fc_b,
                          float* __restrict__ out) {
    float z = logit[0] + fc_b[0];
    out[0] = 1.0f / (1.0f + expf(-z));
}

// ====================== fallback path (device atomics) ======================

__global__ void k_init_f(float* __restrict__ deg, float* __restrict__ accum,
                         float* __restrict__ logit) {
    int i = blockIdx.x * blockDim.x + threadIdx.x;
    if (i < N_NODES) {
        deg[i] = 1.0f;
        accum[2 * i] = 0.0f;
        accum[2 * i + 1] = 0.0f;
    }
    if (i == 0) logit[0] = 0.0f;
}

__global__ void k_deg_f(const int* __restrict__ col, const float* __restrict__ w,
                        float* __restrict__ deg) {
    int e = blockIdx.x * blockDim.x + threadIdx.x;
    if (e < E_EDGES) atomicAdd(&deg[col[e]], w[e]);
}

__global__ void k_rsqrt_f(float* __restrict__ deg) {
    int i = blockIdx.x * blockDim.x + threadIdx.x;
    if (i < N_NODES) deg[i] = rsqrtf(deg[i]);
}

__global__ void k_prop_f(const int* __restrict__ row, const int* __restrict__ col,
                         const float* __restrict__ w, const float* __restrict__ dis,
                         const float* __restrict__ g, float* __restrict__ accum) {
    int e = blockIdx.x * blockDim.x + threadIdx.x;
    if (e < E_EDGES) {
        int r = row[e], c = col[e];
        float nm = w[e];
        atomicAdd(&accum[2 * c],     g[2 * r] * nm);
        atomicAdd(&accum[2 * c + 1], g[2 * r + 1] * nm);
    }
}

__global__ __launch_bounds__(256) void k_epilogue_f(const float* __restrict__ accum,
                                                    const float* __restrict__ g,
                                                    const float* __restrict__ dis,
                                                    const float* __restrict__ b,
                                                    const float* __restrict__ fc_w,
                                                    float* __restrict__ logit) {
    int i = blockIdx.x * blockDim.x + threadIdx.x;
    float partial = 0.0f;
    if (i < N_NODES) {
        float d = dis[i];
        float o0 = (accum[2 * i]     + g[2 * i])     * d + b[0];
        float o1 = (accum[2 * i + 1] + g[2 * i + 1]) * d + b[1];
        o0 = fmaxf(o0, 0.0f); o1 = fmaxf(o1, 0.0f);
        partial = o0 * fc_w[2 * i] + o1 * fc_w[2 * i + 1];
    }
#pragma unroll
    for (int off = 32; off > 0; off >>= 1)
        partial += __shfl_down(partial, off, 64);
    __shared__ float sdata[4];
    int lane = threadIdx.x & 63, wid = threadIdx.x >> 6;
    if (lane == 0) sdata[wid] = partial;
    __syncthreads();
    if (threadIdx.x == 0)
        atomicAdd(logit, sdata[0] + sdata[1] + sdata[2] + sdata[3]);
}

// ====================== launch ======================

extern "C" void kernel_launch(void* const* d_in, const int* in_sizes, int n_in,
                              void* d_out, int out_size, void* d_ws, size_t ws_size,
                              hipStream_t stream) {
    const float* x   = (const float*)d_in[0];
    const int*   el  = (const int*)d_in[1];    // [2, E] int32 on device
    const float* ea  = (const float*)d_in[2];
    const float* W   = (const float*)d_in[3];
    const float* b   = (const float*)d_in[4];
    const float* fcw = (const float*)d_in[5];
    const float* fcb = (const float*)d_in[6];
    float*       out = (float*)d_out;

    const int* row = el;
    const int* col = el + E_EDGES;

    float* ws = (float*)d_ws;
    const int TB = 256;
    dim3 gN((N_NODES + TB - 1) / TB);
    dim3 gG((N_NODES * 64 + TB - 1) / TB);

    // fast-path ws layout (4B units):
    // g[2N] | dis[N] | logit+pad | cursor[16]+pad | sidx[NR*CAP] | sw[NR*CAP] |
    // rep_deg[NR*SLICES*RN] | rep_acc[NR*SLICES*RN*2]
    size_t o_g    = 0;
    size_t o_dis  = o_g + 2 * N_NODES;
    size_t o_log  = o_dis + N_NODES;
    size_t o_cur  = (o_log + 64) & ~63ull;
    size_t o_sidx = (o_cur + 64) & ~63ull;
    size_t o_sw   = o_sidx + (size_t)NR * CAP;
    size_t o_rd   = o_sw + (size_t)NR * CAP;
    size_t o_ra   = o_rd + (size_t)NR * SLICES * RN;
    size_t need_fast = (o_ra + (size_t)NR * SLICES * RN * 2) * 4;

    if (ws_size >= need_fast) {
        float*    g       = ws + o_g;
        float*    dis     = ws + o_dis;
        float*    logit   = ws + o_log;
        int*      cursor  = (int*)(ws + o_cur);
        unsigned* sidx    = (unsigned*)(ws + o_sidx);
        float*    sw      = ws + o_sw;
        float*    rep_deg = ws + o_rd;
        float*    rep_acc = ws + o_ra;

        k_init    <<<1, 64, 0, stream>>>(cursor, logit);
        k_bucket  <<<SB, 256, 0, stream>>>(row, col, ea, cursor, sidx, sw);
        k_deg_s   <<<NR * SLICES, 1024, 0, stream>>>(sidx, sw, cursor, rep_deg);
        k_dis     <<<gN, TB, 0, stream>>>(rep_deg, dis);
        k_gemv    <<<gG, TB, 0, stream>>>(x, W, dis, g);
        k_prop_s  <<<NR * SLICES, 1024, 0, stream>>>(sidx, sw, cursor, g, rep_acc);
        k_epilogue<<<gN, TB, 0, stream>>>(rep_acc, g, dis, b, fcw, logit);
        k_sigmoid <<<1, 1, 0, stream>>>(logit, fcb, out);
    } else {
        float* deg   = ws;
        float* g     = ws + N_NODES;
        float* accum = ws + 3 * N_NODES;
        float* logit = ws + 5 * N_NODES;
        dim3 gE((E_EDGES + TB - 1) / TB);
        k_init_f    <<<gN, TB, 0, stream>>>(deg, accum, logit);
        k_deg_f     <<<gE, TB, 0, stream>>>(col, ea, deg);
        k_rsqrt_f   <<<gN, TB, 0, stream>>>(deg);
        k_gemv      <<<gG, TB, 0, stream>>>(x, W, deg, g);
        k_prop_f    <<<gE, TB, 0, stream>>>(row, col, ea, deg, g, accum);
        k_epilogue_f<<<gN, TB, 0, stream>>>(accum, g, deg, b, fcw, logit);
        k_sigmoid   <<<1, 1, 0, stream>>>(logit, fcb, out);
    }
}

// Round 7
// 400.806 us; speedup vs baseline: 1.0356x; 1.0356x over previous
//
#include <hip/hip_runtime.h>
#include <math.h>

#define N_NODES 100000
#define F_IN    512
#define E_EDGES 3200000

#define NR     32               // node ranges
#define RN     3125             // nodes per range (NR*RN == N_NODES)
#define SB     640              // bucket scan blocks
#define SCHUNK (E_EDGES / SB)   // 5000 edges per block (multiple of 4)
#define CAP    102400           // record capacity per range (mean 100000)
#define SLICES 16               // slice blocks per range for LDS scatter
#define JBITS  12
#define JMASK  0xFFF            // RN=3125 < 4096

// ctrl block (ints): [0..31]=cursor, [32]=logit(float), [33]=done
#define C_LOGIT 32
#define C_DONE  33

// ============ bucket edges by col-range into packed u64 records ============
__global__ __launch_bounds__(256) void k_bucket(const int* __restrict__ row,
                                                const int* __restrict__ col,
                                                const float* __restrict__ w,
                                                int* __restrict__ ctrl,
                                                unsigned long long* __restrict__ rec) {
    __shared__ int hcnt[NR];
    __shared__ int hbase[NR];
    int t = threadIdx.x;
    if (t < NR) hcnt[t] = 0;
    __syncthreads();
    int base = blockIdx.x * SCHUNK;
    const int* colc = col + base;
    // phase 1: count per range (col streamed once; re-read hits L1)
    for (int i4 = t * 4; i4 < SCHUNK; i4 += 1024) {
        int4 c4 = *(const int4*)(colc + i4);
        atomicAdd(&hcnt[c4.x / RN], 1);
        atomicAdd(&hcnt[c4.y / RN], 1);
        atomicAdd(&hcnt[c4.z / RN], 1);
        atomicAdd(&hcnt[c4.w / RN], 1);
    }
    __syncthreads();
    if (t < NR) {
        hbase[t] = atomicAdd(&ctrl[t], hcnt[t]);   // reserve contiguous run
        hcnt[t] = 0;                               // reuse as intra-block rank
    }
    __syncthreads();
    // phase 2: scatter packed records
    const int* rowc = row + base;
    const float* wc = w + base;
    for (int i4 = t * 4; i4 < SCHUNK; i4 += 1024) {
        int4   c4 = *(const int4*)(colc + i4);
        int4   r4 = *(const int4*)(rowc + i4);
        float4 w4 = *(const float4*)(wc + i4);
#pragma unroll
        for (int q = 0; q < 4; ++q) {
            int c = (&c4.x)[q];
            int r = c / RN;
            int j = c - r * RN;
            int rank = atomicAdd(&hcnt[r], 1);
            int slot = r * CAP + hbase[r] + rank;
            unsigned idx = (unsigned)j | ((unsigned)(&r4.x)[q] << JBITS);
            rec[slot] = ((unsigned long long)__float_as_uint((&w4.x)[q]) << 32) | idx;
        }
    }
}

// ============ deg scatter over bucketed records (LDS tile, slices) ============
__global__ __launch_bounds__(1024) void k_deg_s(const unsigned long long* __restrict__ rec,
                                                const int* __restrict__ ctrl,
                                                float* __restrict__ rep_deg) {
    __shared__ float sdeg[RN];
    int r = blockIdx.x / SLICES, s = blockIdx.x % SLICES;
    int len = ctrl[r];
    int lo = r * CAP + len * s / SLICES;
    int hi = r * CAP + len * (s + 1) / SLICES;
    for (int j = threadIdx.x; j < RN; j += 1024) sdeg[j] = 0.0f;
    __syncthreads();
    for (int i = lo + threadIdx.x; i < hi; i += 1024) {
        unsigned long long u = rec[i];
        atomicAdd(&sdeg[(unsigned)u & JMASK], __uint_as_float((unsigned)(u >> 32)));
    }
    __syncthreads();
    float* out = rep_deg + (size_t)blockIdx.x * RN;
    for (int j = threadIdx.x; j < RN; j += 1024) out[j] = sdeg[j];
}

// ============ fused: dis = rsqrt(1+deg); g = (x @ W) * dis ============
__global__ __launch_bounds__(256) void k_gemv(const float* __restrict__ x,
                                              const float* __restrict__ W,
                                              const float* __restrict__ rep_deg,
                                              float* __restrict__ dis,
                                              float* __restrict__ g) {
    int rowi = (blockIdx.x * blockDim.x + threadIdx.x) >> 6;
    int lane = threadIdx.x & 63;
    if (rowi >= N_NODES) return;
    // replica-reduce deg for this row (lanes 0..15, xor-butterfly in 16-group)
    int rr = rowi / RN, j = rowi - rr * RN;
    float dv = 0.0f;
    if (lane < SLICES) dv = rep_deg[(size_t)(rr * SLICES + lane) * RN + j];
    dv += __shfl_xor(dv, 1, 64);
    dv += __shfl_xor(dv, 2, 64);
    dv += __shfl_xor(dv, 4, 64);
    dv += __shfl_xor(dv, 8, 64);
    // gemv over F_IN
    const float* xr = x + (size_t)rowi * F_IN;
    float a0 = 0.0f, a1 = 0.0f;
#pragma unroll
    for (int c = 0; c < 2; ++c) {
        int k = c * 256 + lane * 4;
        float4 xv  = *(const float4*)(xr + k);
        float4 w01 = *(const float4*)(W + 2 * k);
        float4 w23 = *(const float4*)(W + 2 * k + 4);
        a0 += xv.x * w01.x + xv.y * w01.z + xv.z * w23.x + xv.w * w23.z;
        a1 += xv.x * w01.y + xv.y * w01.w + xv.z * w23.y + xv.w * w23.w;
    }
#pragma unroll
    for (int off = 32; off > 0; off >>= 1) {
        a0 += __shfl_down(a0, off, 64);
        a1 += __shfl_down(a1, off, 64);
    }
    if (lane == 0) {
        float d = rsqrtf(1.0f + dv);      // self-loop weight 1
        dis[rowi] = d;
        g[2 * rowi]     = a0 * d;
        g[2 * rowi + 1] = a1 * d;
    }
}

// ============ message scatter over bucketed records ============
__global__ __launch_bounds__(1024) void k_prop_s(const unsigned long long* __restrict__ rec,
                                                 const int* __restrict__ ctrl,
                                                 const float* __restrict__ g,
                                                 float* __restrict__ rep_acc) {
    __shared__ float sacc[RN * 2];
    int r = blockIdx.x / SLICES, s = blockIdx.x % SLICES;
    int len = ctrl[r];
    int lo = r * CAP + len * s / SLICES;
    int hi = r * CAP + len * (s + 1) / SLICES;
    for (int j = threadIdx.x; j < RN * 2; j += 1024) sacc[j] = 0.0f;
    __syncthreads();
    for (int i = lo + threadIdx.x; i < hi; i += 1024) {
        unsigned long long u = rec[i];
        unsigned idx = (unsigned)u;
        int j  = idx & JMASK;
        int rr = idx >> JBITS;
        float we = __uint_as_float((unsigned)(u >> 32));
        float2 gv = *(const float2*)(g + 2 * rr);
        atomicAdd(&sacc[2 * j],     gv.x * we);
        atomicAdd(&sacc[2 * j + 1], gv.y * we);
    }
    __syncthreads();
    float* out = rep_acc + (size_t)blockIdx.x * (RN * 2);
    for (int j = threadIdx.x; j < RN * 2; j += 1024) out[j] = sacc[j];
}

// ====== epilogue: replica-reduce + self-loop + relu + fc dot + sigmoid ======
__global__ __launch_bounds__(256) void k_epilogue(const float* __restrict__ rep_acc,
                                                  const float* __restrict__ g,
                                                  const float* __restrict__ dis,
                                                  const float* __restrict__ b,
                                                  const float* __restrict__ fc_w,
                                                  const float* __restrict__ fc_b,
                                                  int* __restrict__ ctrl,
                                                  float* __restrict__ out) {
    float* logit = (float*)&ctrl[C_LOGIT];
    int i = blockIdx.x * blockDim.x + threadIdx.x;
    float partial = 0.0f;
    if (i < N_NODES) {
        int r = i / RN, j = i - r * RN;
        const float2* base = (const float2*)rep_acc + (size_t)(r * SLICES) * RN + j;
        float o0 = 0.0f, o1 = 0.0f;
#pragma unroll
        for (int p = 0; p < SLICES; ++p) { float2 v = base[p * RN]; o0 += v.x; o1 += v.y; }
        float d = dis[i];
        o0 = (o0 + g[2 * i])     * d + b[0];   // self-loop term: g[i]*dis[i]
        o1 = (o1 + g[2 * i + 1]) * d + b[1];
        o0 = fmaxf(o0, 0.0f); o1 = fmaxf(o1, 0.0f);
        partial = o0 * fc_w[2 * i] + o1 * fc_w[2 * i + 1];
    }
#pragma unroll
    for (int off = 32; off > 0; off >>= 1)
        partial += __shfl_down(partial, off, 64);
    __shared__ float sdata[4];
    int lane = threadIdx.x & 63, wid = threadIdx.x >> 6;
    if (lane == 0) sdata[wid] = partial;
    __syncthreads();
    if (threadIdx.x == 0) {
        atomicAdd(logit, sdata[0] + sdata[1] + sdata[2] + sdata[3]);
        __threadfence();
        int ticket = atomicAdd(&ctrl[C_DONE], 1);
        if (ticket == (int)gridDim.x - 1) {
            float z = atomicAdd(logit, 0.0f) + fc_b[0];   // coherent read
            out[0] = 1.0f / (1.0f + expf(-z));
        }
    }
}

// ====================== fallback path (device atomics) ======================

__global__ void k_init_f(float* __restrict__ deg, float* __restrict__ accum,
                         float* __restrict__ logit) {
    int i = blockIdx.x * blockDim.x + threadIdx.x;
    if (i < N_NODES) {
        deg[i] = 1.0f;
        accum[2 * i] = 0.0f;
        accum[2 * i + 1] = 0.0f;
    }
    if (i == 0) logit[0] = 0.0f;
}

__global__ void k_deg_f(const int* __restrict__ col, const float* __restrict__ w,
                        float* __restrict__ deg) {
    int e = blockIdx.x * blockDim.x + threadIdx.x;
    if (e < E_EDGES) atomicAdd(&deg[col[e]], w[e]);
}

__global__ void k_rsqrt_f(float* __restrict__ deg) {
    int i = blockIdx.x * blockDim.x + threadIdx.x;
    if (i < N_NODES) deg[i] = rsqrtf(deg[i]);
}

__global__ __launch_bounds__(256) void k_gemv_f(const float* __restrict__ x,
                                                const float* __restrict__ W,
                                                const float* __restrict__ dis,
                                                float* __restrict__ g) {
    int rowi = (blockIdx.x * blockDim.x + threadIdx.x) >> 6;
    int lane = threadIdx.x & 63;
    if (rowi >= N_NODES) return;
    const float* xr = x + (size_t)rowi * F_IN;
    float a0 = 0.0f, a1 = 0.0f;
#pragma unroll
    for (int c = 0; c < 2; ++c) {
        int k = c * 256 + lane * 4;
        float4 xv  = *(const float4*)(xr + k);
        float4 w01 = *(const float4*)(W + 2 * k);
        float4 w23 = *(const float4*)(W + 2 * k + 4);
        a0 += xv.x * w01.x + xv.y * w01.z + xv.z * w23.x + xv.w * w23.z;
        a1 += xv.x * w01.y + xv.y * w01.w + xv.z * w23.y + xv.w * w23.w;
    }
#pragma unroll
    for (int off = 32; off > 0; off >>= 1) {
        a0 += __shfl_down(a0, off, 64);
        a1 += __shfl_down(a1, off, 64);
    }
    if (lane == 0) {
        float d = dis[rowi];
        g[2 * rowi] = a0 * d;
        g[2 * rowi + 1] = a1 * d;
    }
}

__global__ void k_prop_f(const int* __restrict__ row, const int* __restrict__ col,
                         const float* __restrict__ w, const float* __restrict__ g,
                         float* __restrict__ accum) {
    int e = blockIdx.x * blockDim.x + threadIdx.x;
    if (e < E_EDGES) {
        int r = row[e], c = col[e];
        atomicAdd(&accum[2 * c],     g[2 * r] * w[e]);
        atomicAdd(&accum[2 * c + 1], g[2 * r + 1] * w[e]);
    }
}

__global__ __launch_bounds__(256) void k_epilogue_f(const float* __restrict__ accum,
                                                    const float* __restrict__ g,
                                                    const float* __restrict__ dis,
                                                    const float* __restrict__ b,
                                                    const float* __restrict__ fc_w,
                                                    float* __restrict__ logit) {
    int i = blockIdx.x * blockDim.x + threadIdx.x;
    float partial = 0.0f;
    if (i < N_NODES) {
        float d = dis[i];
        float o0 = (accum[2 * i]     + g[2 * i])     * d + b[0];
        float o1 = (accum[2 * i + 1] + g[2 * i + 1]) * d + b[1];
        o0 = fmaxf(o0, 0.0f); o1 = fmaxf(o1, 0.0f);
        partial = o0 * fc_w[2 * i] + o1 * fc_w[2 * i + 1];
    }
#pragma unroll
    for (int off = 32; off > 0; off >>= 1)
        partial += __shfl_down(partial, off, 64);
    __shared__ float sdata[4];
    int lane = threadIdx.x & 63, wid = threadIdx.x >> 6;
    if (lane == 0) sdata[wid] = partial;
    __syncthreads();
    if (threadIdx.x == 0)
        atomicAdd(logit, sdata[0] + sdata[1] + sdata[2] + sdata[3]);
}

__global__ void k_sigmoid_f(const float* __restrict__ logit,
                            const float* __restrict__ fc_b,
                            float* __restrict__ out) {
    float z = logit[0] + fc_b[0];
    out[0] = 1.0f / (1.0f + expf(-z));
}

// ====================== launch ======================

extern "C" void kernel_launch(void* const* d_in, const int* in_sizes, int n_in,
                              void* d_out, int out_size, void* d_ws, size_t ws_size,
                              hipStream_t stream) {
    const float* x   = (const float*)d_in[0];
    const int*   el  = (const int*)d_in[1];    // [2, E] int32 on device
    const float* ea  = (const float*)d_in[2];
    const float* W   = (const float*)d_in[3];
    const float* b   = (const float*)d_in[4];
    const float* fcw = (const float*)d_in[5];
    const float* fcb = (const float*)d_in[6];
    float*       out = (float*)d_out;

    const int* row = el;
    const int* col = el + E_EDGES;

    float* ws = (float*)d_ws;
    const int TB = 256;
    dim3 gN((N_NODES + TB - 1) / TB);
    dim3 gG((N_NODES * 64 + TB - 1) / TB);

    // fast-path ws layout (4B units):
    // ctrl[64] | g[2N] | dis[N] | pad | rec[NR*CAP (u64)] | rep_deg | rep_acc
    size_t o_ctrl = 0;
    size_t o_g    = 64;
    size_t o_dis  = o_g + 2 * N_NODES;
    size_t o_rec  = (o_dis + N_NODES + 63) & ~63ull;          // 8B-aligned (even)
    size_t o_rd   = o_rec + (size_t)NR * CAP * 2;             // records are u64
    size_t o_ra   = o_rd + (size_t)NR * SLICES * RN;
    size_t need_fast = (o_ra + (size_t)NR * SLICES * RN * 2) * 4;

    if (ws_size >= need_fast) {
        int*                ctrl    = (int*)(ws + o_ctrl);
        float*              g       = ws + o_g;
        float*              dis     = ws + o_dis;
        unsigned long long* rec     = (unsigned long long*)(ws + o_rec);
        float*              rep_deg = ws + o_rd;
        float*              rep_acc = ws + o_ra;

        hipMemsetAsync(ctrl, 0, 64 * sizeof(int), stream);
        k_bucket  <<<SB, 256, 0, stream>>>(row, col, ea, ctrl, rec);
        k_deg_s   <<<NR * SLICES, 1024, 0, stream>>>(rec, ctrl, rep_deg);
        k_gemv    <<<gG, TB, 0, stream>>>(x, W, rep_deg, dis, g);
        k_prop_s  <<<NR * SLICES, 1024, 0, stream>>>(rec, ctrl, g, rep_acc);
        k_epilogue<<<gN, TB, 0, stream>>>(rep_acc, g, dis, b, fcw, fcb, ctrl, out);
    } else {
        float* deg   = ws;
        float* g     = ws + N_NODES;
        float* accum = ws + 3 * N_NODES;
        float* logit = ws + 5 * N_NODES;
        dim3 gE((E_EDGES + TB - 1) / TB);
        k_init_f    <<<gN, TB, 0, stream>>>(deg, accum, logit);
        k_deg_f     <<<gE, TB, 0, stream>>>(col, ea, deg);
        k_rsqrt_f   <<<gN, TB, 0, stream>>>(deg);
        k_gemv_f    <<<gG, TB, 0, stream>>>(x, W, deg, g);
        k_prop_f    <<<gE, TB, 0, stream>>>(row, col, ea, g, accum);
        k_epilogue_f<<<gN, TB, 0, stream>>>(accum, g, deg, b, fcw, logit);
        k_sigmoid_f <<<1, 1, 0, stream>>>(logit, fcb, out);
    }
}